// Round 2
// baseline (587.412 us; speedup 1.0000x reference)
//
#include <hip/hip_runtime.h>

// Point2Voxel: scatter-mean of point features into a B x 64^3 voxel grid.
// Outputs (flat, in order): masked_pc[N*3], voxel_feats[B*V*32],
// voxel_counts[B*V], inst_flag[B]  -- all float32.
//
// Binning matches XLA's compiled arithmetic: `t / 0.05` canonicalized to
// `t * 20.0f` (separate f32 roundings, NO FMA -> contract(off) LOAD-BEARING).
// Evidence: R2 (f32 div) 2.36, R3 (f64 div) 2.80, R4 (mul) PASS 0.0039.
//
// R6 scheme: gather, not scatter. Per-voxel linked lists (atomicExch push)
// built in ws; one gather kernel writes every feats/counts byte EXACTLY once.
//
// R7 NEUTRAL: block-aggregated inst_flag changed nothing (462->466 = noise).
// Lesson: same-line stores are absorbed by per-XCD L2s, no device-wide
// serialization. The ~200us of unexplained time is NOT inst_flag.
//
// R8 (this round): ABLATION PROBE. Top-5 rocprof rows are all ~183us harness
// poison fills (1.158 GB), so p2v_build/p2v_gather durations are invisible
// (<180us each). We launch a CLONE of gather writing to ws scratch; the
// dur_us delta vs R7 (465.6) IS gather's marginal cost X.
//   X ~ 50-75us  -> gather healthy/BW-bound; build+poison floor dominates.
//   X >~ 150us   -> gather latency-sick -> CSR rewrite next round (clone will
//                   also surface in top-5 with its own counters).
// Real outputs are produced by the UNCHANGED kernels first -> bit-identical.
// REMOVE THE PROBE after reading the result.

static constexpr int kNX  = 64;
static constexpr int kNYZ = 64 * 64;
static constexpr int kV   = 64 * 64 * 64;
static constexpr int kB   = 8;
static constexpr int kC   = 32;

// ---------------- fast path: linked-list gather ----------------

// Kernel A: per-point. masked_pc, validity, list push, block-aggregated
// inst_flag. NOTE: no early returns -- __syncthreads must be uniform.
__global__ void __launch_bounds__(256) p2v_build(
    const float* __restrict__ pc, const int* __restrict__ bid,
    float* __restrict__ masked_pc, int* __restrict__ head,
    int* __restrict__ nxt, float* __restrict__ inst_flag, int n)
{
#pragma clang fp contract(off) reassociate(off)
  __shared__ int sflag[kB];
  if (threadIdx.x < kB) sflag[threadIdx.x] = 0;
  __syncthreads();

  int i = blockIdx.x * blockDim.x + threadIdx.x;

  const float HALF     = (float)(0.5 * 64 * 0.05);  // 1.60000002384f
  const float INV_UNIT = 20.0f;                      // XLA: /0.05 -> *20.0f

  if (i < n) {
    float x = pc[3 * i + 0];
    float y = pc[3 * i + 1];
    float z = pc[3 * i + 2];
    int   b = bid[i];

    bool valid = (fabsf(x) <= HALF) && (fabsf(y) <= HALF) && (fabsf(z) <= HALF);

    masked_pc[3 * i + 0] = valid ? x : 0.0f;
    masked_pc[3 * i + 1] = valid ? y : 0.0f;
    masked_pc[3 * i + 2] = valid ? z : 0.0f;

    if (valid) {
      sflag[b] = 1;  // LDS, benign same-value race

      float tx = x + HALF;
      float ty = y + HALF;
      float tz = z + HALF;
      int ix = (int)(tx * INV_UNIT);
      int iy = (int)(ty * INV_UNIT);
      int iz = (int)(tz * INV_UNIT);
      ix = min(max(ix, 0), kNX - 1);
      iy = min(max(iy, 0), kNX - 1);
      iz = min(max(iz, 0), kNX - 1);

      int lin = b * kV + ix * kNYZ + iy * kNX + iz;
      nxt[i] = atomicExch(head + lin, i);  // lock-free stack push
    }
  }

  __syncthreads();
  if (threadIdx.x < kB && sflag[threadIdx.x] != 0)
    inst_flag[threadIdx.x] = 1.0f;  // benign race: same value
}

// Kernel B: gather. 8 lanes per voxel, each lane owns 4 channels (float4).
// A wave covers 8 voxels: head reads broadcast per voxel-group, feat reads
// and feats/counts writes fully coalesced.
__global__ void __launch_bounds__(256) p2v_gather(
    const float* __restrict__ feat, const int* __restrict__ head,
    const int* __restrict__ nxt, float* __restrict__ voxel_feats,
    float* __restrict__ voxel_counts)
{
#pragma clang fp contract(off) reassociate(off)
  int gid = blockIdx.x * blockDim.x + threadIdx.x;  // < B*V*8
  int v  = gid >> 3;
  int c4 = (gid & 7) * 4;
  if (v >= kB * kV) return;

  float4 sum = make_float4(0.f, 0.f, 0.f, 0.f);
  int cnt = 0;
  int h = head[v];
  while (h >= 0) {
    const float4 f = *(const float4*)(feat + (size_t)h * kC + c4);
    sum.x += f.x; sum.y += f.y; sum.z += f.z; sum.w += f.w;
    ++cnt;
    h = nxt[h];
  }

  if (cnt >= 2) {
    double dc = (double)cnt;  // IEEE f32-equivalent quotient via double
    sum.x = (float)((double)sum.x / dc);
    sum.y = (float)((double)sum.y / dc);
    sum.z = (float)((double)sum.z / dc);
    sum.w = (float)((double)sum.w / dc);
  }
  *(float4*)(voxel_feats + (size_t)v * kC + c4) = sum;

  if (c4 == 0) voxel_counts[v] = (float)cnt;
}

// ---------------- fallback path (ws too small): R4/R5 atomic scheme --------

__global__ void __launch_bounds__(256) p2v_main_fb(
    const float* __restrict__ pc, const float* __restrict__ feat,
    const int* __restrict__ bid, float* __restrict__ masked_pc,
    float* __restrict__ voxel_feats, float* __restrict__ voxel_counts,
    float* __restrict__ inst_flag, int n)
{
#pragma clang fp contract(off) reassociate(off)
  int i = blockIdx.x * blockDim.x + threadIdx.x;
  if (i >= n) return;
  const float HALF = (float)(0.5 * 64 * 0.05);
  const float INV_UNIT = 20.0f;
  float x = pc[3 * i + 0], y = pc[3 * i + 1], z = pc[3 * i + 2];
  bool valid = (fabsf(x) <= HALF) && (fabsf(y) <= HALF) && (fabsf(z) <= HALF);
  masked_pc[3 * i + 0] = valid ? x : 0.0f;
  masked_pc[3 * i + 1] = valid ? y : 0.0f;
  masked_pc[3 * i + 2] = valid ? z : 0.0f;
  if (!valid) return;
  int ix = (int)((x + HALF) * INV_UNIT);
  int iy = (int)((y + HALF) * INV_UNIT);
  int iz = (int)((z + HALF) * INV_UNIT);
  ix = min(max(ix, 0), kNX - 1);
  iy = min(max(iy, 0), kNX - 1);
  iz = min(max(iz, 0), kNX - 1);
  int b = bid[i];
  size_t lin = (size_t)b * kV + (size_t)(ix * kNYZ + iy * kNX + iz);
  atomicAdd(voxel_counts + lin, 1.0f);
  inst_flag[b] = 1.0f;
  float* dst = voxel_feats + lin * kC;
  const float* src = feat + (size_t)i * kC;
#pragma unroll
  for (int c = 0; c < kC; ++c) atomicAdd(dst + c, src[c]);
}

__global__ void __launch_bounds__(256) p2v_finalize_fb(
    float* __restrict__ voxel_feats, const float* __restrict__ voxel_counts)
{
#pragma clang fp contract(off) reassociate(off)
  int v = blockIdx.x * blockDim.x + threadIdx.x;
  if (v >= kB * kV) return;
  float c = voxel_counts[v];
  if (c >= 2.0f) {
    float* p = voxel_feats + (size_t)v * kC;
#pragma unroll
    for (int k = 0; k < kC; ++k) p[k] = (float)((double)p[k] / (double)c);
  }
}

// ---------------------------------------------------------------------------

extern "C" void kernel_launch(void* const* d_in, const int* in_sizes, int n_in,
                              void* d_out, int out_size, void* d_ws, size_t ws_size,
                              hipStream_t stream) {
  const float* pc   = (const float*)d_in[0];
  const float* feat = (const float*)d_in[1];
  const int*   bid  = (const int*)d_in[2];
  float* out = (float*)d_out;

  int n = in_sizes[0] / 3;

  float* masked_pc    = out;
  float* voxel_feats  = out + (size_t)3 * n;
  float* voxel_counts = voxel_feats + (size_t)kB * kV * kC;
  float* inst_flag    = voxel_counts + (size_t)kB * kV;

  const int block = 256;
  size_t need = (size_t)kB * kV * sizeof(int) + (size_t)n * sizeof(int);

  if (ws_size >= need) {
    // Fast path: linked-list gather.
    int* head = (int*)d_ws;              // B*V ints (8 MB)
    int* nxt  = head + (size_t)kB * kV;  // n ints (4 MB)

    // head := -1 (0xFF bytes); inst_flag := 0 (only outputs not written
    // unconditionally by a kernel).
    hipMemsetAsync(head, 0xFF, (size_t)kB * kV * sizeof(int), stream);
    hipMemsetAsync(inst_flag, 0, kB * sizeof(float), stream);

    p2v_build<<<(n + block - 1) / block, block, 0, stream>>>(
        pc, bid, masked_pc, head, nxt, inst_flag, n);

    long long ng = (long long)kB * kV * 8;  // 8 lanes per voxel
    p2v_gather<<<(int)((ng + block - 1) / block), block, 0, stream>>>(
        feat, head, nxt, voxel_feats, voxel_counts);

    // ---- R8 ABLATION PROBE (remove after reading): clone gather into ws
    // scratch. Reads same head/nxt/feat (read-only); real outputs already
    // written above and bit-identical to R7. dur_us delta == gather cost.
    size_t probe_off = ((size_t)kB * kV + (size_t)n) * sizeof(int);
    probe_off = (probe_off + 255) & ~(size_t)255;  // 16B+ align for float4
    size_t probe_need = probe_off +
        (size_t)kB * kV * kC * sizeof(float) +  // scratch feats (268 MB)
        (size_t)kB * kV * sizeof(float);        // scratch counts (8 MB)
    if (ws_size >= probe_need) {
      float* s_feats  = (float*)((char*)d_ws + probe_off);
      float* s_counts = s_feats + (size_t)kB * kV * kC;
      p2v_gather<<<(int)((ng + block - 1) / block), block, 0, stream>>>(
          feat, head, nxt, s_feats, s_counts);
    }
    // ---- end probe ----
  } else {
    // Fallback: proven R5 atomic scheme (needs no ws).
    size_t tail_floats = (size_t)kB * kV * kC + (size_t)kB * kV + kB;
    hipMemsetAsync(voxel_feats, 0, tail_floats * sizeof(float), stream);
    p2v_main_fb<<<(n + block - 1) / block, block, 0, stream>>>(
        pc, feat, bid, masked_pc, voxel_feats, voxel_counts, inst_flag, n);
    int nv = kB * kV;
    p2v_finalize_fb<<<(nv + block - 1) / block, block, 0, stream>>>(
        voxel_feats, voxel_counts);
  }
}

// Round 3
// 510.343 us; speedup vs baseline: 1.1510x; 1.1510x over previous
//
#include <hip/hip_runtime.h>

// Point2Voxel: scatter-mean of point features into a B x 64^3 voxel grid.
// Outputs (flat, in order): masked_pc[N*3], voxel_feats[B*V*32],
// voxel_counts[B*V], inst_flag[B]  -- all float32.
//
// Binning matches XLA's compiled arithmetic: `t / 0.05` canonicalized to
// `t * 20.0f` (separate f32 roundings, NO FMA -> contract(off) LOAD-BEARING).
// Evidence: R2 (f32 div) 2.36, R3 (f64 div) 2.80, R4 (mul) PASS 0.0039.
//
// R6 scheme: gather, not scatter. Per-voxel linked lists (atomicExch push)
// built in ws; one gather kernel writes every feats/counts byte EXACTLY once.
//
// R7 NEUTRAL: inst_flag hot-line theory falsified (462->466 = noise).
// R8 PROBE: gather marginal cost = 121.8us (warm lower bound; ideal 62us).
//   Accounting: one 183.5us ws-poison fill per iteration (top-5 = 5 iters of
//   the same fill) => build ~= 112-158us vs ~8us ideal. BUILD is the
//   biggest unexplained consumer.
//
// R9 (this round): PROBE BUILD. Full clone of p2v_build into ws scratch
// (own 0xFF-memset head, own nxt/masked/flag), launched after the real
// pipeline. dur delta vs 465.6 == build cost B.
//   B ~ 110-160 -> confirmed; next round sub-ablate (atomics vs strided IO).
//   B ~ 25-40   -> build healthy; pivot to gather (CSR / chase removal).
// REMOVE THE PROBE after reading the result.

static constexpr int kNX  = 64;
static constexpr int kNYZ = 64 * 64;
static constexpr int kV   = 64 * 64 * 64;
static constexpr int kB   = 8;
static constexpr int kC   = 32;

// ---------------- fast path: linked-list gather ----------------

// Kernel A: per-point. masked_pc, validity, list push, block-aggregated
// inst_flag. NOTE: no early returns -- __syncthreads must be uniform.
__global__ void __launch_bounds__(256) p2v_build(
    const float* __restrict__ pc, const int* __restrict__ bid,
    float* __restrict__ masked_pc, int* __restrict__ head,
    int* __restrict__ nxt, float* __restrict__ inst_flag, int n)
{
#pragma clang fp contract(off) reassociate(off)
  __shared__ int sflag[kB];
  if (threadIdx.x < kB) sflag[threadIdx.x] = 0;
  __syncthreads();

  int i = blockIdx.x * blockDim.x + threadIdx.x;

  const float HALF     = (float)(0.5 * 64 * 0.05);  // 1.60000002384f
  const float INV_UNIT = 20.0f;                      // XLA: /0.05 -> *20.0f

  if (i < n) {
    float x = pc[3 * i + 0];
    float y = pc[3 * i + 1];
    float z = pc[3 * i + 2];
    int   b = bid[i];

    bool valid = (fabsf(x) <= HALF) && (fabsf(y) <= HALF) && (fabsf(z) <= HALF);

    masked_pc[3 * i + 0] = valid ? x : 0.0f;
    masked_pc[3 * i + 1] = valid ? y : 0.0f;
    masked_pc[3 * i + 2] = valid ? z : 0.0f;

    if (valid) {
      sflag[b] = 1;  // LDS, benign same-value race

      float tx = x + HALF;
      float ty = y + HALF;
      float tz = z + HALF;
      int ix = (int)(tx * INV_UNIT);
      int iy = (int)(ty * INV_UNIT);
      int iz = (int)(tz * INV_UNIT);
      ix = min(max(ix, 0), kNX - 1);
      iy = min(max(iy, 0), kNX - 1);
      iz = min(max(iz, 0), kNX - 1);

      int lin = b * kV + ix * kNYZ + iy * kNX + iz;
      nxt[i] = atomicExch(head + lin, i);  // lock-free stack push
    }
  }

  __syncthreads();
  if (threadIdx.x < kB && sflag[threadIdx.x] != 0)
    inst_flag[threadIdx.x] = 1.0f;  // benign race: same value
}

// Kernel B: gather. 8 lanes per voxel, each lane owns 4 channels (float4).
// A wave covers 8 voxels: head reads broadcast per voxel-group, feat reads
// and feats/counts writes fully coalesced.
__global__ void __launch_bounds__(256) p2v_gather(
    const float* __restrict__ feat, const int* __restrict__ head,
    const int* __restrict__ nxt, float* __restrict__ voxel_feats,
    float* __restrict__ voxel_counts)
{
#pragma clang fp contract(off) reassociate(off)
  int gid = blockIdx.x * blockDim.x + threadIdx.x;  // < B*V*8
  int v  = gid >> 3;
  int c4 = (gid & 7) * 4;
  if (v >= kB * kV) return;

  float4 sum = make_float4(0.f, 0.f, 0.f, 0.f);
  int cnt = 0;
  int h = head[v];
  while (h >= 0) {
    const float4 f = *(const float4*)(feat + (size_t)h * kC + c4);
    sum.x += f.x; sum.y += f.y; sum.z += f.z; sum.w += f.w;
    ++cnt;
    h = nxt[h];
  }

  if (cnt >= 2) {
    double dc = (double)cnt;  // IEEE f32-equivalent quotient via double
    sum.x = (float)((double)sum.x / dc);
    sum.y = (float)((double)sum.y / dc);
    sum.z = (float)((double)sum.z / dc);
    sum.w = (float)((double)sum.w / dc);
  }
  *(float4*)(voxel_feats + (size_t)v * kC + c4) = sum;

  if (c4 == 0) voxel_counts[v] = (float)cnt;
}

// ---------------- fallback path (ws too small): R4/R5 atomic scheme --------

__global__ void __launch_bounds__(256) p2v_main_fb(
    const float* __restrict__ pc, const float* __restrict__ feat,
    const int* __restrict__ bid, float* __restrict__ masked_pc,
    float* __restrict__ voxel_feats, float* __restrict__ voxel_counts,
    float* __restrict__ inst_flag, int n)
{
#pragma clang fp contract(off) reassociate(off)
  int i = blockIdx.x * blockDim.x + threadIdx.x;
  if (i >= n) return;
  const float HALF = (float)(0.5 * 64 * 0.05);
  const float INV_UNIT = 20.0f;
  float x = pc[3 * i + 0], y = pc[3 * i + 1], z = pc[3 * i + 2];
  bool valid = (fabsf(x) <= HALF) && (fabsf(y) <= HALF) && (fabsf(z) <= HALF);
  masked_pc[3 * i + 0] = valid ? x : 0.0f;
  masked_pc[3 * i + 1] = valid ? y : 0.0f;
  masked_pc[3 * i + 2] = valid ? z : 0.0f;
  if (!valid) return;
  int ix = (int)((x + HALF) * INV_UNIT);
  int iy = (int)((y + HALF) * INV_UNIT);
  int iz = (int)((z + HALF) * INV_UNIT);
  ix = min(max(ix, 0), kNX - 1);
  iy = min(max(iy, 0), kNX - 1);
  iz = min(max(iz, 0), kNX - 1);
  int b = bid[i];
  size_t lin = (size_t)b * kV + (size_t)(ix * kNYZ + iy * kNX + iz);
  atomicAdd(voxel_counts + lin, 1.0f);
  inst_flag[b] = 1.0f;
  float* dst = voxel_feats + lin * kC;
  const float* src = feat + (size_t)i * kC;
#pragma unroll
  for (int c = 0; c < kC; ++c) atomicAdd(dst + c, src[c]);
}

__global__ void __launch_bounds__(256) p2v_finalize_fb(
    float* __restrict__ voxel_feats, const float* __restrict__ voxel_counts)
{
#pragma clang fp contract(off) reassociate(off)
  int v = blockIdx.x * blockDim.x + threadIdx.x;
  if (v >= kB * kV) return;
  float c = voxel_counts[v];
  if (c >= 2.0f) {
    float* p = voxel_feats + (size_t)v * kC;
#pragma unroll
    for (int k = 0; k < kC; ++k) p[k] = (float)((double)p[k] / (double)c);
  }
}

// ---------------------------------------------------------------------------

extern "C" void kernel_launch(void* const* d_in, const int* in_sizes, int n_in,
                              void* d_out, int out_size, void* d_ws, size_t ws_size,
                              hipStream_t stream) {
  const float* pc   = (const float*)d_in[0];
  const float* feat = (const float*)d_in[1];
  const int*   bid  = (const int*)d_in[2];
  float* out = (float*)d_out;

  int n = in_sizes[0] / 3;

  float* masked_pc    = out;
  float* voxel_feats  = out + (size_t)3 * n;
  float* voxel_counts = voxel_feats + (size_t)kB * kV * kC;
  float* inst_flag    = voxel_counts + (size_t)kB * kV;

  const int block = 256;
  size_t need = (size_t)kB * kV * sizeof(int) + (size_t)n * sizeof(int);

  if (ws_size >= need) {
    // Fast path: linked-list gather.
    int* head = (int*)d_ws;              // B*V ints (8 MB)
    int* nxt  = head + (size_t)kB * kV;  // n ints (4 MB)

    // head := -1 (0xFF bytes); inst_flag := 0 (only outputs not written
    // unconditionally by a kernel).
    hipMemsetAsync(head, 0xFF, (size_t)kB * kV * sizeof(int), stream);
    hipMemsetAsync(inst_flag, 0, kB * sizeof(float), stream);

    p2v_build<<<(n + block - 1) / block, block, 0, stream>>>(
        pc, bid, masked_pc, head, nxt, inst_flag, n);

    long long ng = (long long)kB * kV * 8;  // 8 lanes per voxel
    p2v_gather<<<(int)((ng + block - 1) / block), block, 0, stream>>>(
        feat, head, nxt, voxel_feats, voxel_counts);

    // ---- R9 ABLATION PROBE (remove after reading): clone p2v_build into ws
    // scratch with identical initial conditions (fresh 0xFF head). Real
    // outputs already written above; clone touches only ws scratch.
    // dur_us delta vs 465.6 == build cost B.
    size_t probe_off = ((size_t)kB * kV + (size_t)n) * sizeof(int);
    probe_off = (probe_off + 255) & ~(size_t)255;
    size_t probe_bytes = (size_t)kB * kV * sizeof(int)   // s_head 8MB
                       + (size_t)n * sizeof(int)         // s_nxt  4MB
                       + (size_t)3 * n * sizeof(float)   // s_masked 12MB
                       + 256;                            // s_flag + pad
    if (ws_size >= probe_off + probe_bytes) {
      char* base = (char*)d_ws + probe_off;
      int*   s_head   = (int*)base;
      int*   s_nxt    = s_head + (size_t)kB * kV;
      float* s_masked = (float*)(s_nxt + n);
      float* s_flag   = s_masked + (size_t)3 * n;
      hipMemsetAsync(s_head, 0xFF, (size_t)kB * kV * sizeof(int), stream);
      p2v_build<<<(n + block - 1) / block, block, 0, stream>>>(
          pc, bid, s_masked, s_head, s_nxt, s_flag, n);
    }
    // ---- end probe ----
  } else {
    // Fallback: proven R5 atomic scheme (needs no ws).
    size_t tail_floats = (size_t)kB * kV * kC + (size_t)kB * kV + kB;
    hipMemsetAsync(voxel_feats, 0, tail_floats * sizeof(float), stream);
    p2v_main_fb<<<(n + block - 1) / block, block, 0, stream>>>(
        pc, feat, bid, masked_pc, voxel_feats, voxel_counts, inst_flag, n);
    int nv = kB * kV;
    p2v_finalize_fb<<<(nv + block - 1) / block, block, 0, stream>>>(
        voxel_feats, voxel_counts);
  }
}

// Round 5
// 449.944 us; speedup vs baseline: 1.3055x; 1.1342x over previous
//
#include <hip/hip_runtime.h>

// Point2Voxel: scatter-mean of point features into a B x 64^3 voxel grid.
// Outputs (flat, in order): masked_pc[N*3], voxel_feats[B*V*32],
// voxel_counts[B*V], inst_flag[B]  -- all float32.
//
// Binning matches XLA's compiled arithmetic: `t / 0.05` canonicalized to
// `t * 20.0f` (separate f32 roundings, NO FMA -> contract(off) LOAD-BEARING).
// Evidence: R2 (f32 div) 2.36, R3 (f64 div) 2.80, R4 (mul) PASS 0.0039.
//
// R6 scheme: gather, not scatter. Per-voxel linked lists (atomicExch push)
// built in ws; one gather kernel writes every feats/counts byte EXACTLY once.
//
// R7 NEUTRAL: inst_flag hot-line theory falsified (462->466 = noise).
// R8 PROBE: gather warm cost = 121.8us (ideal ~67us).
// R9 PROBE: build cost = ~43us (ideal ~8us). Ledger: 183.5 ws-fill + ~46
//   out-fill (harness floor ~230us) + build ~50 + gather ~145 ~= 465.6.
// R10 COMPILE FAIL: __builtin_nontemporal_* rejects HIP_vector_type float4.
//
// R11 (this round): same WRITE-ALLOCATE theory, fixed types. Harness fill
// writes 1.158 GB with FETCH_SIZE=14.5 KB -> streaming stores don't
// allocate. Our plain stores fetch-on-write-miss: gather's 276 MB write
// stream adds ~276 MB hidden FETCH (~44us). Fix: nontemporal load/store via
// clang ext_vector_type(4) float (native vector -> builtin accepts; same
// 16B layout as float4). Cache hints only -> bit-identical outputs.
// Predict dur 465.6 -> 405-430. If <15us delta: falsified -> CSR gather A/B.

static constexpr int kNX  = 64;
static constexpr int kNYZ = 64 * 64;
static constexpr int kV   = 64 * 64 * 64;
static constexpr int kB   = 8;
static constexpr int kC   = 32;

typedef float f32x4 __attribute__((ext_vector_type(4)));  // nt-able float4

// ---------------- fast path: linked-list gather ----------------

// Kernel A: per-point. masked_pc, validity, list push, inst_flag.
__global__ void __launch_bounds__(256) p2v_build(
    const float* __restrict__ pc, const int* __restrict__ bid,
    float* __restrict__ masked_pc, int* __restrict__ head,
    int* __restrict__ nxt, float* __restrict__ inst_flag, int n)
{
#pragma clang fp contract(off) reassociate(off)
  int i = blockIdx.x * blockDim.x + threadIdx.x;
  if (i >= n) return;

  const float HALF     = (float)(0.5 * 64 * 0.05);  // 1.60000002384f
  const float INV_UNIT = 20.0f;                      // XLA: /0.05 -> *20.0f

  float x = pc[3 * i + 0];
  float y = pc[3 * i + 1];
  float z = pc[3 * i + 2];
  int   b = bid[i];

  bool valid = (fabsf(x) <= HALF) && (fabsf(y) <= HALF) && (fabsf(z) <= HALF);

  __builtin_nontemporal_store(valid ? x : 0.0f, masked_pc + 3 * i + 0);
  __builtin_nontemporal_store(valid ? y : 0.0f, masked_pc + 3 * i + 1);
  __builtin_nontemporal_store(valid ? z : 0.0f, masked_pc + 3 * i + 2);

  if (!valid) return;

  float tx = x + HALF;
  float ty = y + HALF;
  float tz = z + HALF;
  int ix = (int)(tx * INV_UNIT);
  int iy = (int)(ty * INV_UNIT);
  int iz = (int)(tz * INV_UNIT);
  ix = min(max(ix, 0), kNX - 1);
  iy = min(max(iy, 0), kNX - 1);
  iz = min(max(iz, 0), kNX - 1);

  int lin = b * kV + ix * kNYZ + iy * kNX + iz;
  // Gather runs in a later kernel (full barrier between) -> nt store of nxt
  // is safe relative to the atomicExch publish.
  __builtin_nontemporal_store(atomicExch(head + lin, i), nxt + i);
  inst_flag[b] = 1.0f;  // benign race: same value (R7: aggregation neutral)
}

// Kernel B: gather. 8 lanes per voxel, each lane owns 4 channels (float4).
// A wave covers 8 voxels: head reads broadcast per voxel-group, feat reads
// and feats/counts writes fully coalesced. nt load/store: read-once /
// write-once streams, avoid L2/LLC write-allocate fetch.
__global__ void __launch_bounds__(256) p2v_gather(
    const float* __restrict__ feat, const int* __restrict__ head,
    const int* __restrict__ nxt, float* __restrict__ voxel_feats,
    float* __restrict__ voxel_counts)
{
#pragma clang fp contract(off) reassociate(off)
  int gid = blockIdx.x * blockDim.x + threadIdx.x;  // < B*V*8
  int v  = gid >> 3;
  int c4 = (gid & 7) * 4;
  if (v >= kB * kV) return;

  f32x4 sum = (f32x4)(0.0f);
  int cnt = 0;
  int h = head[v];
  while (h >= 0) {
    const f32x4 f =
        __builtin_nontemporal_load((const f32x4*)(feat + (size_t)h * kC + c4));
    sum.x += f.x; sum.y += f.y; sum.z += f.z; sum.w += f.w;
    ++cnt;
    h = nxt[h];
  }

  if (cnt >= 2) {
    double dc = (double)cnt;  // IEEE f32-equivalent quotient via double
    sum.x = (float)((double)sum.x / dc);
    sum.y = (float)((double)sum.y / dc);
    sum.z = (float)((double)sum.z / dc);
    sum.w = (float)((double)sum.w / dc);
  }
  __builtin_nontemporal_store(sum, (f32x4*)(voxel_feats + (size_t)v * kC + c4));

  if (c4 == 0) __builtin_nontemporal_store((float)cnt, voxel_counts + v);
}

// ---------------- fallback path (ws too small): R4/R5 atomic scheme --------

__global__ void __launch_bounds__(256) p2v_main_fb(
    const float* __restrict__ pc, const float* __restrict__ feat,
    const int* __restrict__ bid, float* __restrict__ masked_pc,
    float* __restrict__ voxel_feats, float* __restrict__ voxel_counts,
    float* __restrict__ inst_flag, int n)
{
#pragma clang fp contract(off) reassociate(off)
  int i = blockIdx.x * blockDim.x + threadIdx.x;
  if (i >= n) return;
  const float HALF = (float)(0.5 * 64 * 0.05);
  const float INV_UNIT = 20.0f;
  float x = pc[3 * i + 0], y = pc[3 * i + 1], z = pc[3 * i + 2];
  bool valid = (fabsf(x) <= HALF) && (fabsf(y) <= HALF) && (fabsf(z) <= HALF);
  masked_pc[3 * i + 0] = valid ? x : 0.0f;
  masked_pc[3 * i + 1] = valid ? y : 0.0f;
  masked_pc[3 * i + 2] = valid ? z : 0.0f;
  if (!valid) return;
  int ix = (int)((x + HALF) * INV_UNIT);
  int iy = (int)((y + HALF) * INV_UNIT);
  int iz = (int)((z + HALF) * INV_UNIT);
  ix = min(max(ix, 0), kNX - 1);
  iy = min(max(iy, 0), kNX - 1);
  iz = min(max(iz, 0), kNX - 1);
  int b = bid[i];
  size_t lin = (size_t)b * kV + (size_t)(ix * kNYZ + iy * kNX + iz);
  atomicAdd(voxel_counts + lin, 1.0f);
  inst_flag[b] = 1.0f;
  float* dst = voxel_feats + lin * kC;
  const float* src = feat + (size_t)i * kC;
#pragma unroll
  for (int c = 0; c < kC; ++c) atomicAdd(dst + c, src[c]);
}

__global__ void __launch_bounds__(256) p2v_finalize_fb(
    float* __restrict__ voxel_feats, const float* __restrict__ voxel_counts)
{
#pragma clang fp contract(off) reassociate(off)
  int v = blockIdx.x * blockDim.x + threadIdx.x;
  if (v >= kB * kV) return;
  float c = voxel_counts[v];
  if (c >= 2.0f) {
    float* p = voxel_feats + (size_t)v * kC;
#pragma unroll
    for (int k = 0; k < kC; ++k) p[k] = (float)((double)p[k] / (double)c);
  }
}

// ---------------------------------------------------------------------------

extern "C" void kernel_launch(void* const* d_in, const int* in_sizes, int n_in,
                              void* d_out, int out_size, void* d_ws, size_t ws_size,
                              hipStream_t stream) {
  const float* pc   = (const float*)d_in[0];
  const float* feat = (const float*)d_in[1];
  const int*   bid  = (const int*)d_in[2];
  float* out = (float*)d_out;

  int n = in_sizes[0] / 3;

  float* masked_pc    = out;
  float* voxel_feats  = out + (size_t)3 * n;
  float* voxel_counts = voxel_feats + (size_t)kB * kV * kC;
  float* inst_flag    = voxel_counts + (size_t)kB * kV;

  const int block = 256;
  size_t need = (size_t)kB * kV * sizeof(int) + (size_t)n * sizeof(int);

  if (ws_size >= need) {
    // Fast path: linked-list gather.
    int* head = (int*)d_ws;              // B*V ints (8 MB)
    int* nxt  = head + (size_t)kB * kV;  // n ints (4 MB)

    // head := -1 (0xFF bytes); inst_flag := 0 (only outputs not written
    // unconditionally by a kernel).
    (void)hipMemsetAsync(head, 0xFF, (size_t)kB * kV * sizeof(int), stream);
    (void)hipMemsetAsync(inst_flag, 0, kB * sizeof(float), stream);

    p2v_build<<<(n + block - 1) / block, block, 0, stream>>>(
        pc, bid, masked_pc, head, nxt, inst_flag, n);

    long long ng = (long long)kB * kV * 8;  // 8 lanes per voxel
    p2v_gather<<<(int)((ng + block - 1) / block), block, 0, stream>>>(
        feat, head, nxt, voxel_feats, voxel_counts);
  } else {
    // Fallback: proven R5 atomic scheme (needs no ws).
    size_t tail_floats = (size_t)kB * kV * kC + (size_t)kB * kV + kB;
    (void)hipMemsetAsync(voxel_feats, 0, tail_floats * sizeof(float), stream);
    p2v_main_fb<<<(n + block - 1) / block, block, 0, stream>>>(
        pc, feat, bid, masked_pc, voxel_feats, voxel_counts, inst_flag, n);
    int nv = kB * kV;
    p2v_finalize_fb<<<(nv + block - 1) / block, block, 0, stream>>>(
        voxel_feats, voxel_counts);
  }
}